// Round 4
// baseline (273.187 us; speedup 1.0000x reference)
//
#include <hip/hip_runtime.h>

// B=2, C=4, D=64, H=256, W=256. 7-point |Laplacian| MSE between softmax probs
// (classes 1..3) and one-hot targets, mean over all 3*B*D*H*W terms.
//
// Plane-march in d, accumulator form. Tile = 32(w) x 30(h) interior; block =
// 256 threads = 8 quad-cols x 32 rows (rows 0 and 31 are the h-halo, staged
// by their owner threads — no dedicated halo waves). w-halo = 2 cols x 30
// rows = 60 scalars, owned by threads 0..59. IDD=4 planes per block ->
// grid = 8(w) x 9(h) x 16(d) x 2(b) = 2304 blocks = 9/CU exactly.
//
// KEY FIX vs R3: in-loop barriers are raw `s_waitcnt lgkmcnt(0); s_barrier`
// (LDS ordering only). __syncthreads() would emit s_waitcnt vmcnt(0) and
// drain the next-plane prefetch every iteration — that drain was R3's ~57 us
// of stall. No cross-thread global-memory communication happens in-loop, so
// skipping the vmcnt drain is safe.

#define CS   (1 << 22)           // per-batch spatial size (d,h,w)
#define NTOT_INV (1.0f / 25165824.0f)
#define BIAS3 ((8 << 20) | (8 << 10) | 8)   // +8 bias per 10-bit one-hot field
#define BAR() asm volatile("s_waitcnt lgkmcnt(0)\n\ts_barrier" ::: "memory")

struct Plane { float4 p1, p2, p3; int4 oh; };
struct Raw   { float4 q0, q1, q2, q3; int4 qt; };

__device__ __forceinline__ void smax1(float x0, float x1, float x2, float x3,
                                      float vm, float& p1, float& p2, float& p3) {
    float m  = fmaxf(fmaxf(x0, x1), fmaxf(x2, x3));
    float e0 = __expf(x0 - m);
    float e1 = __expf(x1 - m);
    float e2 = __expf(x2 - m);
    float e3 = __expf(x3 - m);
    float r  = vm * __builtin_amdgcn_rcpf(e0 + e1 + e2 + e3);
    p1 = e1 * r; p2 = e2 * r; p3 = e3 * r;
}

// class k in {1,2,3} -> 1 << ((k-1)*10); class 0 / masked -> 0
__device__ __forceinline__ int ohenc(int t, int msk) {
    int nz = (t > 0) ? 1 : 0;
    return (nz << (((t - 1) & 3) * 10)) & msk;
}

__device__ __forceinline__ Raw loadRaw(const float* __restrict__ L,
                                       const int* __restrict__ T,
                                       int lB, int tB, int d) {
    Raw r; const int off = d << 16;
    r.q0 = *(const float4*)(L + lB + off);
    r.q1 = *(const float4*)(L + lB + off + CS);
    r.q2 = *(const float4*)(L + lB + off + 2 * CS);
    r.q3 = *(const float4*)(L + lB + off + 3 * CS);
    r.qt = *(const int4*)(T + tB + off);
    return r;
}

__device__ __forceinline__ void cook(const Raw& r, float vm, int ohm, Plane& p) {
    smax1(r.q0.x, r.q1.x, r.q2.x, r.q3.x, vm, p.p1.x, p.p2.x, p.p3.x);
    smax1(r.q0.y, r.q1.y, r.q2.y, r.q3.y, vm, p.p1.y, p.p2.y, p.p3.y);
    smax1(r.q0.z, r.q1.z, r.q2.z, r.q3.z, vm, p.p1.z, p.p2.z, p.p3.z);
    smax1(r.q0.w, r.q1.w, r.q2.w, r.q3.w, vm, p.p1.w, p.p2.w, p.p3.w);
    p.oh.x = ohenc(r.qt.x, ohm); p.oh.y = ohenc(r.qt.y, ohm);
    p.oh.z = ohenc(r.qt.z, ohm); p.oh.w = ohenc(r.qt.w, ohm);
}

__global__ __launch_bounds__(256, 5) void boundary_loss_kernel(
        const float* __restrict__ L,
        const int*   __restrict__ T,
        float*       __restrict__ out) {
    const int tid = threadIdx.x;
    const int tw  = tid & 7;          // quad column 0..7 (4 w-voxels each)
    const int th  = tid >> 3;         // row 0..31 (rows 0,31 = h-halo)
    int bi = blockIdx.x;
    const int wt = bi & 7;  bi >>= 3;
    const int dt = bi & 15; bi >>= 4;
    const int ht = bi % 9;
    const int b  = bi / 9;

    const int   h0 = ht * 30;
    const int   h  = h0 + th - 1;
    const bool  hv = ((unsigned)h < 256u);
    const float vm = hv ? 1.f : 0.f;
    const int   ohm = hv ? ~0 : 0;
    const int   w0 = wt << 5;
    const int   sp = ((hv ? h : 0) << 8) | (w0 + (tw << 2));
    const int   tBase = b * CS + sp;
    const int   lBase = (b << 2) * CS + sp;
    const bool  live  = (th >= 1) && (th <= 30) && hv;
    const int   d0 = dt << 2;

    // w-halo column duty: threads 0..29 = left col, 30..59 = right col
    const bool  hd   = (tid < 60);
    const int   side = (tid >= 30) ? 1 : 0;
    const int   hr   = side ? (tid - 29) : (tid + 1);    // interior row 1..30
    const int   hh   = h0 + hr - 1;
    const int   hwv  = side ? (w0 + 32) : (w0 - 1);
    const bool  hvv  = hd && ((unsigned)hh < 256u) && ((unsigned)hwv < 256u);
    const float hvm  = hvv ? 1.f : 0.f;
    const int   hohm = hvv ? ~0 : 0;
    const int   hsp  = ((hvv ? hh : 0) << 8) | (hvv ? hwv : 0);
    const int   htB  = b * CS + hsp;
    const int   hlB  = (b << 2) * CS + hsp;

    __shared__ float P1[32][32], P2[32][32], P3[32][32];
    __shared__ int   OHS[32][32];
    __shared__ float HL1[2][32], HL2[2][32], HL3[2][32];
    __shared__ int   HLO[2][32];

    // loop-invariant w-neighbor pointers (halo col for edge quads)
    const int c0 = tw << 2;
    const float* lp1 = (tw == 0) ? &HL1[0][th] : &P1[th][c0 - 1];
    const float* lp2 = (tw == 0) ? &HL2[0][th] : &P2[th][c0 - 1];
    const float* lp3 = (tw == 0) ? &HL3[0][th] : &P3[th][c0 - 1];
    const int*   lpo = (tw == 0) ? &HLO[0][th] : &OHS[th][c0 - 1];
    const float* rp1 = (tw == 7) ? &HL1[1][th] : &P1[th][c0 + 4];
    const float* rp2 = (tw == 7) ? &HL2[1][th] : &P2[th][c0 + 4];
    const float* rp3 = (tw == 7) ? &HL3[1][th] : &P3[th][c0 + 4];
    const int*   rpo = (tw == 7) ? &HLO[1][th] : &OHS[th][c0 + 4];

    Plane cur, acc;
    float hc1 = 0.f, hc2 = 0.f, hc3 = 0.f; int hco = 0;   // halo col, cur plane
    float accv = 0.f;

    // seed accumulator with plane d0-1 (zero-padded below d=0)
    if (dt > 0) {
        Raw r = loadRaw(L, T, lBase, tBase, d0 - 1);
        cook(r, vm, ohm, acc);
    } else {
        acc.p1 = acc.p2 = acc.p3 = make_float4(0.f, 0.f, 0.f, 0.f);
        acc.oh = make_int4(0, 0, 0, 0);
    }
    acc.oh.x += BIAS3; acc.oh.y += BIAS3; acc.oh.z += BIAS3; acc.oh.w += BIAS3;

    // plane d0 -> cur (+ halo col)
    {
        Raw r = loadRaw(L, T, lBase, tBase, d0);
        cook(r, vm, ohm, cur);
        if (hd) {
            const int off = d0 << 16;
            float x0 = L[hlB + off], x1 = L[hlB + off + CS];
            float x2 = L[hlB + off + 2 * CS], x3 = L[hlB + off + 3 * CS];
            int   t  = T[htB + off];
            smax1(x0, x1, x2, x3, hvm, hc1, hc2, hc3);
            hco = ohenc(t, hohm);
        }
    }

    for (int i = 0; i < 4; ++i) {
        const int  dn = d0 + i + 1;
        const bool dv = (dn < 64);               // block-uniform
        Raw r;
        float hx0 = 0.f, hx1 = 0.f, hx2 = 0.f, hx3 = 0.f; int hqt = 0;
        if (dv) {
            r = loadRaw(L, T, lBase, tBase, dn);  // stays in flight across BARs
            if (hd) {
                const int off = dn << 16;
                hx0 = L[hlB + off]; hx1 = L[hlB + off + CS];
                hx2 = L[hlB + off + 2 * CS]; hx3 = L[hlB + off + 3 * CS];
                hqt = T[htB + off];
            }
        }

        BAR();   // prior step's stencil readers done (lgkm only, vmcnt live)
        *(float4*)&P1[th][c0] = cur.p1;
        *(float4*)&P2[th][c0] = cur.p2;
        *(float4*)&P3[th][c0] = cur.p3;
        *(int4*)&OHS[th][c0]  = cur.oh;
        if (hd) {
            HL1[side][hr] = hc1; HL2[side][hr] = hc2; HL3[side][hr] = hc3;
            HLO[side][hr] = hco;
        }
        BAR();   // plane visible to all waves

        if (live) {
            float4 u, dn4; float lf, rt;
            u = *(float4*)&P1[th - 1][c0]; dn4 = *(float4*)&P1[th + 1][c0];
            lf = *lp1; rt = *rp1;
            acc.p1.x += u.x + dn4.x + lf        + cur.p1.y - 6.f * cur.p1.x;
            acc.p1.y += u.y + dn4.y + cur.p1.x  + cur.p1.z - 6.f * cur.p1.y;
            acc.p1.z += u.z + dn4.z + cur.p1.y  + cur.p1.w - 6.f * cur.p1.z;
            acc.p1.w += u.w + dn4.w + cur.p1.z  + rt       - 6.f * cur.p1.w;
            u = *(float4*)&P2[th - 1][c0]; dn4 = *(float4*)&P2[th + 1][c0];
            lf = *lp2; rt = *rp2;
            acc.p2.x += u.x + dn4.x + lf        + cur.p2.y - 6.f * cur.p2.x;
            acc.p2.y += u.y + dn4.y + cur.p2.x  + cur.p2.z - 6.f * cur.p2.y;
            acc.p2.z += u.z + dn4.z + cur.p2.y  + cur.p2.w - 6.f * cur.p2.z;
            acc.p2.w += u.w + dn4.w + cur.p2.z  + rt       - 6.f * cur.p2.w;
            u = *(float4*)&P3[th - 1][c0]; dn4 = *(float4*)&P3[th + 1][c0];
            lf = *lp3; rt = *rp3;
            acc.p3.x += u.x + dn4.x + lf        + cur.p3.y - 6.f * cur.p3.x;
            acc.p3.y += u.y + dn4.y + cur.p3.x  + cur.p3.z - 6.f * cur.p3.y;
            acc.p3.z += u.z + dn4.z + cur.p3.y  + cur.p3.w - 6.f * cur.p3.z;
            acc.p3.w += u.w + dn4.w + cur.p3.z  + rt       - 6.f * cur.p3.w;

            int4 iu = *(int4*)&OHS[th - 1][c0];
            int4 id = *(int4*)&OHS[th + 1][c0];
            int  il = *lpo, ir = *rpo;
            acc.oh.x += iu.x + id.x + il        + cur.oh.y - 6 * cur.oh.x;
            acc.oh.y += iu.y + id.y + cur.oh.x  + cur.oh.z - 6 * cur.oh.y;
            acc.oh.z += iu.z + id.z + cur.oh.y  + cur.oh.w - 6 * cur.oh.z;
            acc.oh.w += iu.w + id.w + cur.oh.z  + ir       - 6 * cur.oh.w;
        }

        // softmax of prefetched next plane (first use of the in-flight loads)
        Plane nx;
        float hn1 = 0.f, hn2 = 0.f, hn3 = 0.f; int hno = 0;
        if (dv) {
            cook(r, vm, ohm, nx);
            if (hd) {
                smax1(hx0, hx1, hx2, hx3, hvm, hn1, hn2, hn3);
                hno = ohenc(hqt, hohm);
            }
        } else {
            nx.p1 = nx.p2 = nx.p3 = make_float4(0.f, 0.f, 0.f, 0.f);
            nx.oh = make_int4(0, 0, 0, 0);
        }

        if (live) {
            int t0 = acc.oh.x + nx.oh.x, t1 = acc.oh.y + nx.oh.y;
            int t2 = acc.oh.z + nx.oh.z, t3 = acc.oh.w + nx.oh.w;
            float lp, lt, df;
            lp = fabsf(acc.p1.x + nx.p1.x); lt = fabsf((float)((t0 & 1023) - 8));          df = lp - lt; accv = fmaf(df, df, accv);
            lp = fabsf(acc.p2.x + nx.p2.x); lt = fabsf((float)(((t0 >> 10) & 1023) - 8));  df = lp - lt; accv = fmaf(df, df, accv);
            lp = fabsf(acc.p3.x + nx.p3.x); lt = fabsf((float)(((t0 >> 20) & 1023) - 8));  df = lp - lt; accv = fmaf(df, df, accv);
            lp = fabsf(acc.p1.y + nx.p1.y); lt = fabsf((float)((t1 & 1023) - 8));          df = lp - lt; accv = fmaf(df, df, accv);
            lp = fabsf(acc.p2.y + nx.p2.y); lt = fabsf((float)(((t1 >> 10) & 1023) - 8));  df = lp - lt; accv = fmaf(df, df, accv);
            lp = fabsf(acc.p3.y + nx.p3.y); lt = fabsf((float)(((t1 >> 20) & 1023) - 8));  df = lp - lt; accv = fmaf(df, df, accv);
            lp = fabsf(acc.p1.z + nx.p1.z); lt = fabsf((float)((t2 & 1023) - 8));          df = lp - lt; accv = fmaf(df, df, accv);
            lp = fabsf(acc.p2.z + nx.p2.z); lt = fabsf((float)(((t2 >> 10) & 1023) - 8));  df = lp - lt; accv = fmaf(df, df, accv);
            lp = fabsf(acc.p3.z + nx.p3.z); lt = fabsf((float)(((t2 >> 20) & 1023) - 8));  df = lp - lt; accv = fmaf(df, df, accv);
            lp = fabsf(acc.p1.w + nx.p1.w); lt = fabsf((float)((t3 & 1023) - 8));          df = lp - lt; accv = fmaf(df, df, accv);
            lp = fabsf(acc.p2.w + nx.p2.w); lt = fabsf((float)(((t3 >> 10) & 1023) - 8));  df = lp - lt; accv = fmaf(df, df, accv);
            lp = fabsf(acc.p3.w + nx.p3.w); lt = fabsf((float)(((t3 >> 20) & 1023) - 8));  df = lp - lt; accv = fmaf(df, df, accv);
        }

        // rotate planes: cur seeds the next accumulator's "+1 from below"
        acc.p1 = cur.p1; acc.p2 = cur.p2; acc.p3 = cur.p3;
        acc.oh.x = cur.oh.x + BIAS3; acc.oh.y = cur.oh.y + BIAS3;
        acc.oh.z = cur.oh.z + BIAS3; acc.oh.w = cur.oh.w + BIAS3;
        cur = nx;
        hc1 = hn1; hc2 = hn2; hc3 = hn3; hco = hno;
    }

    // block reduction: wave shuffle -> LDS -> one atomic
    for (int o = 32; o > 0; o >>= 1) accv += __shfl_down(accv, o, 64);
    __shared__ float wsum[4];
    if ((tid & 63) == 0) wsum[tid >> 6] = accv;
    __syncthreads();
    if (tid == 0)
        atomicAdd(out, (wsum[0] + wsum[1] + wsum[2] + wsum[3]) * NTOT_INV);
}

extern "C" void kernel_launch(void* const* d_in, const int* in_sizes, int n_in,
                              void* d_out, int out_size, void* d_ws, size_t ws_size,
                              hipStream_t stream) {
    const float* logits  = (const float*)d_in[0];
    const int*   targets = (const int*)d_in[1];
    float*       out     = (float*)d_out;

    hipMemsetAsync(out, 0, sizeof(float), stream);   // d_out is poisoned 0xAA
    boundary_loss_kernel<<<2304, 256, 0, stream>>>(logits, targets, out);
}

// Round 5
// 240.821 us; speedup vs baseline: 1.1344x; 1.1344x over previous
//
#include <hip/hip_runtime.h>

// B=2, C=4, D=64, H=256, W=256. 7-point |Laplacian| MSE between softmax probs
// (classes 1..3) and one-hot targets, mean over all 3*B*D*H*W terms.
//
// Plane-march in d, accumulator form. Tile = 32(w) x 30(h) interior; block =
// 256 threads = 8 quad-cols x 32 rows (rows 0/31 are the h-halo, staged by
// their owner threads). w-halo = 2 cols x 30 rows = 60 scalars owned by
// threads 0..59. IDD=8 planes/block -> grid = 8(w) x 9(h) x 8(d) x 2(b)
// = 1152 blocks (~4.5/CU).
//
// In-loop barriers are raw `s_waitcnt lgkmcnt(0); s_barrier` (LDS ordering
// only) so the next-plane global prefetch stays in flight across them
// (__syncthreads would emit s_waitcnt vmcnt(0) and drain it - R3's stall).
// R4 lesson: NO __launch_bounds__ min-waves clause and NO struct-valued
// conditional prefetch - both together caused scratch spills (WRITE_SIZE
// 32 KB -> 32 MB). Prefetch is unconditional (d clamped to 63, validity
// folded into the softmax/one-hot masks) into named float4s.

#define CS   (1 << 22)           // per-batch spatial size (d,h,w)
#define NTOT_INV (1.0f / 25165824.0f)
#define BIAS3 ((8 << 20) | (8 << 10) | 8)   // +8 bias per 10-bit one-hot field
#define BAR() asm volatile("s_waitcnt lgkmcnt(0)\n\ts_barrier" ::: "memory")

__device__ __forceinline__ void smax1(float x0, float x1, float x2, float x3,
                                      float vm, float& p1, float& p2, float& p3) {
    float m  = fmaxf(fmaxf(x0, x1), fmaxf(x2, x3));
    float e0 = __expf(x0 - m);
    float e1 = __expf(x1 - m);
    float e2 = __expf(x2 - m);
    float e3 = __expf(x3 - m);
    float r  = vm * __builtin_amdgcn_rcpf(e0 + e1 + e2 + e3);
    p1 = e1 * r; p2 = e2 * r; p3 = e3 * r;
}

// class k in {1,2,3} -> 1 << ((k-1)*10); class 0 / masked -> 0
__device__ __forceinline__ int ohenc(int t, int msk) {
    int nz = (t > 0) ? 1 : 0;
    return (nz << (((t - 1) & 3) * 10)) & msk;
}

__global__ __launch_bounds__(256) void boundary_loss_kernel(
        const float* __restrict__ L,
        const int*   __restrict__ T,
        float*       __restrict__ out) {
    const int tid = threadIdx.x;
    const int tw  = tid & 7;          // quad column 0..7 (4 w-voxels each)
    const int th  = tid >> 3;         // row 0..31 (rows 0,31 = h-halo)
    int bi = blockIdx.x;
    const int wt = bi & 7;  bi >>= 3;
    const int dt = bi & 7;  bi >>= 3;
    const int ht = bi % 9;
    const int b  = bi / 9;

    const int   h0 = ht * 30;
    const int   h  = h0 + th - 1;
    const bool  hv = ((unsigned)h < 256u);
    const float vm = hv ? 1.f : 0.f;
    const int   ohm = hv ? ~0 : 0;
    const int   w0 = wt << 5;
    const int   sp = ((hv ? h : 0) << 8) | (w0 + (tw << 2));
    const int   tBase = b * CS + sp;
    const int   lBase = (b << 2) * CS + sp;
    const bool  live  = (th >= 1) && (th <= 30) && hv;
    const int   d0 = dt << 3;

    // w-halo column duty: threads 0..29 = left col, 30..59 = right col
    const bool  hd   = (tid < 60);
    const int   side = (tid >= 30) ? 1 : 0;
    const int   hr   = side ? (tid - 29) : (tid + 1);    // interior row 1..30
    const int   hh   = h0 + hr - 1;
    const int   hwv  = side ? (w0 + 32) : (w0 - 1);
    const bool  hvv  = hd && ((unsigned)hh < 256u) && ((unsigned)hwv < 256u);
    const float hvm  = hvv ? 1.f : 0.f;
    const int   hohm = hvv ? ~0 : 0;
    const int   hsp  = ((hvv ? hh : 0) << 8) | (hvv ? hwv : 0);
    const int   htB  = b * CS + hsp;
    const int   hlB  = (b << 2) * CS + hsp;

    __shared__ float P1[32][32], P2[32][32], P3[32][32];
    __shared__ int   OHS[32][32];
    __shared__ float HL1[2][32], HL2[2][32], HL3[2][32];
    __shared__ int   HLO[2][32];

    // loop-invariant w-neighbor pointers (halo col for edge quads)
    const int c0 = tw << 2;
    const float* lp1 = (tw == 0) ? &HL1[0][th] : &P1[th][c0 - 1];
    const float* lp2 = (tw == 0) ? &HL2[0][th] : &P2[th][c0 - 1];
    const float* lp3 = (tw == 0) ? &HL3[0][th] : &P3[th][c0 - 1];
    const int*   lpo = (tw == 0) ? &HLO[0][th] : &OHS[th][c0 - 1];
    const float* rp1 = (tw == 7) ? &HL1[1][th] : &P1[th][c0 + 4];
    const float* rp2 = (tw == 7) ? &HL2[1][th] : &P2[th][c0 + 4];
    const float* rp3 = (tw == 7) ? &HL3[1][th] : &P3[th][c0 + 4];
    const int*   rpo = (tw == 7) ? &HLO[1][th] : &OHS[th][c0 + 4];

    float4 c1, c2, c3; int4 coh;      // current plane probs / packed one-hot
    float4 a1, a2, a3; int4 aoh;      // running Laplacian accumulator
    float hc1 = 0.f, hc2 = 0.f, hc3 = 0.f; int hco = 0;   // halo col, cur plane
    float accv = 0.f;

    // ---- seed accumulator with plane d0-1 (zero outside volume) ----
    {
        const int  off = (dt > 0 ? d0 - 1 : 0) << 16;
        const float svm  = (dt > 0) ? vm : 0.f;
        const int   sohm = (dt > 0) ? ohm : 0;
        float4 q0 = *(const float4*)(L + lBase + off);
        float4 q1 = *(const float4*)(L + lBase + off + CS);
        float4 q2 = *(const float4*)(L + lBase + off + 2 * CS);
        float4 q3 = *(const float4*)(L + lBase + off + 3 * CS);
        int4   qt = *(const int4*)(T + tBase + off);
        smax1(q0.x, q1.x, q2.x, q3.x, svm, a1.x, a2.x, a3.x);
        smax1(q0.y, q1.y, q2.y, q3.y, svm, a1.y, a2.y, a3.y);
        smax1(q0.z, q1.z, q2.z, q3.z, svm, a1.z, a2.z, a3.z);
        smax1(q0.w, q1.w, q2.w, q3.w, svm, a1.w, a2.w, a3.w);
        aoh.x = ohenc(qt.x, sohm) + BIAS3; aoh.y = ohenc(qt.y, sohm) + BIAS3;
        aoh.z = ohenc(qt.z, sohm) + BIAS3; aoh.w = ohenc(qt.w, sohm) + BIAS3;
    }

    // ---- plane d0 -> cur (+ halo col) ----
    {
        const int off = d0 << 16;
        float4 q0 = *(const float4*)(L + lBase + off);
        float4 q1 = *(const float4*)(L + lBase + off + CS);
        float4 q2 = *(const float4*)(L + lBase + off + 2 * CS);
        float4 q3 = *(const float4*)(L + lBase + off + 3 * CS);
        int4   qt = *(const int4*)(T + tBase + off);
        float hx0 = L[hlB + off], hx1 = L[hlB + off + CS];
        float hx2 = L[hlB + off + 2 * CS], hx3 = L[hlB + off + 3 * CS];
        int   hqt = T[htB + off];
        smax1(q0.x, q1.x, q2.x, q3.x, vm, c1.x, c2.x, c3.x);
        smax1(q0.y, q1.y, q2.y, q3.y, vm, c1.y, c2.y, c3.y);
        smax1(q0.z, q1.z, q2.z, q3.z, vm, c1.z, c2.z, c3.z);
        smax1(q0.w, q1.w, q2.w, q3.w, vm, c1.w, c2.w, c3.w);
        coh.x = ohenc(qt.x, ohm); coh.y = ohenc(qt.y, ohm);
        coh.z = ohenc(qt.z, ohm); coh.w = ohenc(qt.w, ohm);
        smax1(hx0, hx1, hx2, hx3, hvm, hc1, hc2, hc3);
        hco = ohenc(hqt, hohm);
    }

    for (int i = 0; i < 8; ++i) {
        const int   dn   = d0 + i + 1;
        const float vmn  = (dn < 64) ? vm : 0.f;     // d-validity folded in
        const int   ohmn = (dn < 64) ? ohm : 0;
        const float hvmn = (dn < 64) ? hvm : 0.f;
        const int   hohmn = (dn < 64) ? hohm : 0;
        const int   off  = (dn < 64 ? dn : 63) << 16;

        // unconditional prefetch — stays in flight across both BARs
        float4 q0 = *(const float4*)(L + lBase + off);
        float4 q1 = *(const float4*)(L + lBase + off + CS);
        float4 q2 = *(const float4*)(L + lBase + off + 2 * CS);
        float4 q3 = *(const float4*)(L + lBase + off + 3 * CS);
        int4   qt = *(const int4*)(T + tBase + off);
        float hx0 = L[hlB + off], hx1 = L[hlB + off + CS];
        float hx2 = L[hlB + off + 2 * CS], hx3 = L[hlB + off + 3 * CS];
        int   hqt = T[htB + off];

        BAR();   // prior step's stencil readers done (lgkm only, vmcnt live)
        *(float4*)&P1[th][c0] = c1;
        *(float4*)&P2[th][c0] = c2;
        *(float4*)&P3[th][c0] = c3;
        *(int4*)&OHS[th][c0]  = coh;
        if (hd) {
            HL1[side][hr] = hc1; HL2[side][hr] = hc2; HL3[side][hr] = hc3;
            HLO[side][hr] = hco;
        }
        BAR();   // plane visible to all waves

        if (live) {
            float4 u, dn4; float lf, rt;
            u = *(float4*)&P1[th - 1][c0]; dn4 = *(float4*)&P1[th + 1][c0];
            lf = *lp1; rt = *rp1;
            a1.x += u.x + dn4.x + lf   + c1.y - 6.f * c1.x;
            a1.y += u.y + dn4.y + c1.x + c1.z - 6.f * c1.y;
            a1.z += u.z + dn4.z + c1.y + c1.w - 6.f * c1.z;
            a1.w += u.w + dn4.w + c1.z + rt   - 6.f * c1.w;
            u = *(float4*)&P2[th - 1][c0]; dn4 = *(float4*)&P2[th + 1][c0];
            lf = *lp2; rt = *rp2;
            a2.x += u.x + dn4.x + lf   + c2.y - 6.f * c2.x;
            a2.y += u.y + dn4.y + c2.x + c2.z - 6.f * c2.y;
            a2.z += u.z + dn4.z + c2.y + c2.w - 6.f * c2.z;
            a2.w += u.w + dn4.w + c2.z + rt   - 6.f * c2.w;
            u = *(float4*)&P3[th - 1][c0]; dn4 = *(float4*)&P3[th + 1][c0];
            lf = *lp3; rt = *rp3;
            a3.x += u.x + dn4.x + lf   + c3.y - 6.f * c3.x;
            a3.y += u.y + dn4.y + c3.x + c3.z - 6.f * c3.y;
            a3.z += u.z + dn4.z + c3.y + c3.w - 6.f * c3.z;
            a3.w += u.w + dn4.w + c3.z + rt   - 6.f * c3.w;

            int4 iu = *(int4*)&OHS[th - 1][c0];
            int4 id = *(int4*)&OHS[th + 1][c0];
            int  il = *lpo, ir = *rpo;
            aoh.x += iu.x + id.x + il    + coh.y - 6 * coh.x;
            aoh.y += iu.y + id.y + coh.x + coh.z - 6 * coh.y;
            aoh.z += iu.z + id.z + coh.y + coh.w - 6 * coh.z;
            aoh.w += iu.w + id.w + coh.z + ir    - 6 * coh.w;
        }

        // softmax of prefetched next plane (first use of the in-flight loads)
        float4 n1, n2, n3; int4 noh;
        smax1(q0.x, q1.x, q2.x, q3.x, vmn, n1.x, n2.x, n3.x);
        smax1(q0.y, q1.y, q2.y, q3.y, vmn, n1.y, n2.y, n3.y);
        smax1(q0.z, q1.z, q2.z, q3.z, vmn, n1.z, n2.z, n3.z);
        smax1(q0.w, q1.w, q2.w, q3.w, vmn, n1.w, n2.w, n3.w);
        noh.x = ohenc(qt.x, ohmn); noh.y = ohenc(qt.y, ohmn);
        noh.z = ohenc(qt.z, ohmn); noh.w = ohenc(qt.w, ohmn);
        float hn1, hn2, hn3;
        smax1(hx0, hx1, hx2, hx3, hvmn, hn1, hn2, hn3);
        int hno = ohenc(hqt, hohmn);

        if (live) {
            int t0 = aoh.x + noh.x, t1 = aoh.y + noh.y;
            int t2 = aoh.z + noh.z, t3 = aoh.w + noh.w;
            float lp, lt, df;
            lp = fabsf(a1.x + n1.x); lt = fabsf((float)((t0 & 1023) - 8));          df = lp - lt; accv = fmaf(df, df, accv);
            lp = fabsf(a2.x + n2.x); lt = fabsf((float)(((t0 >> 10) & 1023) - 8));  df = lp - lt; accv = fmaf(df, df, accv);
            lp = fabsf(a3.x + n3.x); lt = fabsf((float)(((t0 >> 20) & 1023) - 8));  df = lp - lt; accv = fmaf(df, df, accv);
            lp = fabsf(a1.y + n1.y); lt = fabsf((float)((t1 & 1023) - 8));          df = lp - lt; accv = fmaf(df, df, accv);
            lp = fabsf(a2.y + n2.y); lt = fabsf((float)(((t1 >> 10) & 1023) - 8));  df = lp - lt; accv = fmaf(df, df, accv);
            lp = fabsf(a3.y + n3.y); lt = fabsf((float)(((t1 >> 20) & 1023) - 8));  df = lp - lt; accv = fmaf(df, df, accv);
            lp = fabsf(a1.z + n1.z); lt = fabsf((float)((t2 & 1023) - 8));          df = lp - lt; accv = fmaf(df, df, accv);
            lp = fabsf(a2.z + n2.z); lt = fabsf((float)(((t2 >> 10) & 1023) - 8));  df = lp - lt; accv = fmaf(df, df, accv);
            lp = fabsf(a3.z + n3.z); lt = fabsf((float)(((t2 >> 20) & 1023) - 8));  df = lp - lt; accv = fmaf(df, df, accv);
            lp = fabsf(a1.w + n1.w); lt = fabsf((float)((t3 & 1023) - 8));          df = lp - lt; accv = fmaf(df, df, accv);
            lp = fabsf(a2.w + n2.w); lt = fabsf((float)(((t3 >> 10) & 1023) - 8));  df = lp - lt; accv = fmaf(df, df, accv);
            lp = fabsf(a3.w + n3.w); lt = fabsf((float)(((t3 >> 20) & 1023) - 8));  df = lp - lt; accv = fmaf(df, df, accv);
        }

        // rotate planes: cur seeds the next accumulator's "+1 from below"
        a1 = c1; a2 = c2; a3 = c3;
        aoh.x = coh.x + BIAS3; aoh.y = coh.y + BIAS3;
        aoh.z = coh.z + BIAS3; aoh.w = coh.w + BIAS3;
        c1 = n1; c2 = n2; c3 = n3; coh = noh;
        hc1 = hn1; hc2 = hn2; hc3 = hn3; hco = hno;
    }

    // block reduction: wave shuffle -> LDS -> one atomic
    for (int o = 32; o > 0; o >>= 1) accv += __shfl_down(accv, o, 64);
    __shared__ float wsum[4];
    if ((tid & 63) == 0) wsum[tid >> 6] = accv;
    __syncthreads();
    if (tid == 0)
        atomicAdd(out, (wsum[0] + wsum[1] + wsum[2] + wsum[3]) * NTOT_INV);
}

extern "C" void kernel_launch(void* const* d_in, const int* in_sizes, int n_in,
                              void* d_out, int out_size, void* d_ws, size_t ws_size,
                              hipStream_t stream) {
    const float* logits  = (const float*)d_in[0];
    const int*   targets = (const int*)d_in[1];
    float*       out     = (float*)d_out;

    hipMemsetAsync(out, 0, sizeof(float), stream);   // d_out is poisoned 0xAA
    boundary_loss_kernel<<<1152, 256, 0, stream>>>(logits, targets, out);
}